// Round 6
// baseline (150.023 us; speedup 1.0000x reference)
//
#include <hip/hip_runtime.h>
#include <stdint.h>

// MPS chain contraction, B=32768, L=256, D=16.
// R13: barrier-free, 4 waves/SIMD, forced-resident 4-set register prefetch.
//   Ledger across R7/R8/R10/R12: MFMA-pipe time 13.8us (= algorithm floor)
//   and VALU time ~20us are invariant; memory is ~10% of L2 share; yet all
//   structures pin at 59-60us -> overlap failure. R7/R8: barrier lockstep
//   (chip-wide alternating VALU/MFMA phases). R10/R12: VGPR=40/56 proves
//   prefetch live-ranges were shortened -> demand loads on the serial chain
//   at only 2 waves/SIMD. Fix: 1024 blocks x 1 chain/wave (4 waves/SIMD),
//   no main-loop barriers, pairs j..j+3 held in named register sets, every
//   issue cluster fenced with sched_barrier(0), manual satisfiable
//   vmcnt(9) waits (queue invariant [PHI(2t)][F(4t)][F(4t+1)][PHI(2t+1)]
//   [F(4t+2)] = 14 outstanding at loop top, verified per step).

typedef short  bf16x8 __attribute__((ext_vector_type(8)));
typedef float  f32x4  __attribute__((ext_vector_type(4)));
typedef int    i32x4  __attribute__((ext_vector_type(4)));
typedef unsigned int u32;

#define NPF 64
#define NPB 63
#define BWD_OFF (NPF*4*64)   // i32x4 units

#define PACK_HI(hi, lo) ((int)__builtin_amdgcn_perm((u32)(hi), (u32)(lo), 0x07060302u))

__device__ __forceinline__ u32 rne_bump(u32 u){ return u + 0x7FFFu + ((u >> 16) & 1u); }

// Pair-fragment table: blocks 0..63 fwd (j=bid), 64..126 bwd (j=bid-64).
// fwd: G[m][cq] = sum_r Ca[cq][p][r]*Cb[r][q][m],  Ca=cm[2j], Cb=cm[2j+1]
// bwd: G[m][cq] = sum_r Ca[m][p][r]*Cb[r][q][cq],  Ca=cm[252-2j], Cb=cm[253-2j]
// lane (m=lane&15, g=lane>>4) packs cols 4g..4g+3 hi (dw0,1) and lo (dw2,3).
__global__ void build_pair_frags(const float* __restrict__ cm, i32x4* __restrict__ ws)
{
  __shared__ float Ca[512], Cb[512];   // [x][p][y] = cm[t][x][p][y]
  const int bid = blockIdx.x;
  const bool fwd = bid < NPF;
  const int j  = fwd ? bid : bid - NPF;
  const int ta = fwd ? 2*j     : 252 - 2*j;
  const int tb = fwd ? 2*j + 1 : 253 - 2*j;
  {
    const float* A = cm + ta*512;
    const float* B = cm + tb*512;
    for (int i = threadIdx.x; i < 512; i += 256){ Ca[i] = A[i]; Cb[i] = B[i]; }
  }
  __syncthreads();
  const int f    = threadIdx.x >> 6;    // combo p*2+q
  const int lane = threadIdx.x & 63;
  const int m    = lane & 15;
  const int g    = lane >> 4;
  const int p    = f >> 1, q = f & 1;
  u32 hi[4], lo[4];
  #pragma unroll
  for (int x = 0; x < 4; ++x){
    const int cq = 4*g + x;
    float acc = 0.f;
    #pragma unroll
    for (int r = 0; r < 16; ++r){
      const float a = fwd ? Ca[cq*32 + p*16 + r] : Ca[m*32 + p*16 + r];
      const float b = fwd ? Cb[r*32 + q*16 + m]  : Cb[r*32 + q*16 + cq];
      acc = fmaf(a, b, acc);
    }
    const u32 u  = __float_as_uint(acc);
    const u32 aa = rne_bump(u);
    const float hf = __uint_as_float(aa & 0xFFFF0000u);
    const u32 bb = rne_bump(__float_as_uint(acc - hf));
    hi[x] = aa >> 16; lo[x] = bb >> 16;
  }
  i32x4 w;
  w[0] = (int)(hi[0] | (hi[1] << 16));
  w[1] = (int)(hi[2] | (hi[3] << 16));
  w[2] = (int)(lo[0] | (lo[1] << 16));
  w[3] = (int)(lo[2] | (lo[3] << 16));
  ws[(fwd ? 0 : BWD_OFF) + (j*4 + f)*64 + lane] = w;
}

__device__ __forceinline__ void make_bfrag(const float (&v)[4], i32x4 &bfr)
{
  const u32 u0 = __float_as_uint(v[0]), u1 = __float_as_uint(v[1]);
  const u32 u2 = __float_as_uint(v[2]), u3 = __float_as_uint(v[3]);
  const float l0 = v[0] - __uint_as_float(u0 & 0xFFFF0000u);
  const float l1 = v[1] - __uint_as_float(u1 & 0xFFFF0000u);
  const float l2 = v[2] - __uint_as_float(u2 & 0xFFFF0000u);
  const float l3 = v[3] - __uint_as_float(u3 & 0xFFFF0000u);
  bfr[0] = PACK_HI(u1, u0);
  bfr[1] = PACK_HI(u3, u2);
  bfr[2] = PACK_HI(__float_as_uint(l1), __float_as_uint(l0));
  bfr[3] = PACK_HI(__float_as_uint(l3), __float_as_uint(l2));
}

__device__ __forceinline__ void pair_step(
    const i32x4 &G0, const i32x4 &G1, const i32x4 &G2, const i32x4 &G3,
    float2 cA, float2 cB, float (&v)[4], i32x4 &bfr)
{
  const float c00 = cA.x*cB.x, c01 = cA.x*cB.y;
  const float c10 = cA.y*cB.x, c11 = cA.y*cB.y;
  i32x4 sw; sw[0]=bfr[2]; sw[1]=bfr[3]; sw[2]=bfr[0]; sw[3]=bfr[1];
  const bf16x8 bh = __builtin_bit_cast(bf16x8, bfr);
  const bf16x8 bs = __builtin_bit_cast(bf16x8, sw);
  const f32x4 z = {0.f,0.f,0.f,0.f};
  __builtin_amdgcn_s_setprio(1);
  f32x4 a00 = __builtin_amdgcn_mfma_f32_16x16x32_bf16(__builtin_bit_cast(bf16x8,G0), bh, z, 0,0,0);
  a00 = __builtin_amdgcn_mfma_f32_16x16x32_bf16(__builtin_bit_cast(bf16x8,G0), bs, a00, 0,0,0);
  f32x4 a01 = __builtin_amdgcn_mfma_f32_16x16x32_bf16(__builtin_bit_cast(bf16x8,G1), bh, z, 0,0,0);
  a01 = __builtin_amdgcn_mfma_f32_16x16x32_bf16(__builtin_bit_cast(bf16x8,G1), bs, a01, 0,0,0);
  f32x4 a10 = __builtin_amdgcn_mfma_f32_16x16x32_bf16(__builtin_bit_cast(bf16x8,G2), bh, z, 0,0,0);
  a10 = __builtin_amdgcn_mfma_f32_16x16x32_bf16(__builtin_bit_cast(bf16x8,G2), bs, a10, 0,0,0);
  f32x4 a11 = __builtin_amdgcn_mfma_f32_16x16x32_bf16(__builtin_bit_cast(bf16x8,G3), bh, z, 0,0,0);
  a11 = __builtin_amdgcn_mfma_f32_16x16x32_bf16(__builtin_bit_cast(bf16x8,G3), bs, a11, 0,0,0);
  __builtin_amdgcn_s_setprio(0);
  #pragma unroll
  for (int i2 = 0; i2 < 4; ++i2)
    v[i2] = c00*a00[i2] + c01*a01[i2] + c10*a10[i2] + c11*a11[i2];
  make_bfrag(v, bfr);
}

#define WAIT9 do { asm volatile("s_waitcnt vmcnt(9)" ::: "memory"); \
                   __builtin_amdgcn_sched_barrier(0); } while(0)
#define SB    __builtin_amdgcn_sched_barrier(0)

__global__ __launch_bounds__(256, 4) void mps_chain(
  const float* __restrict__ phi,
  const float* __restrict__ core_first,
  const float* __restrict__ core_last,
  const float* __restrict__ bias,
  const i32x4* __restrict__ ws,
  float* __restrict__ out)
{
  const int lane = threadIdx.x & 63;
  const int wv   = threadIdx.x >> 6;
  const int b0   = blockIdx.x * 32;
  const int n    = lane & 15;            // sample column
  const int g    = lane >> 4;            // row group / phi quarter
  const int half = wv & 1;
  const int s_in = half*16 + n;
  const bool isFwd = (wv < 2);
  const int dirIdx = isFwd ? 0 : 1;

  __shared__ float red[64*20];           // epilogue reduction only (5 KB)

  const float* phiRow = phi + (size_t)(b0 + s_in) * 512;
  // phi window base: lane covers sample b0+16*half+(lane&15), floats (lane>>4)*4..+3
  const float* phiSrc = phi + (size_t)(b0 + 16*half + (lane & 15)) * 512
                            + (lane >> 4) * 4;

  const i32x4* wsD    = isFwd ? ws : (ws + BWD_OFF);
  const int    maxPr  = isFwd ? NPF - 1 : NPB - 1;
  const i32x4* wsLane = wsD + lane;      // + pr*256 + f*64

  // bpermute byte addrs: window float qt*4+e lives in lane n+16*qt, elem e.
  const int qtF  = isFwd ? 0 : 1;
  const int aQ   = ((lane & 15) + 16*qtF) << 2;
  const int adrA0 = isFwd ? aQ       : aQ + 64;   // fwd fl2,3  | bwd fl10,11
  const int adrB0 = isFwd ? aQ + 64  : aQ + 128;  // fwd fl4,5  | bwd fl12,13
  const int adrA1 = isFwd ? aQ + 64  : aQ;        // fwd fl6,7  | bwd fl6,7
  const int adrB1 = isFwd ? aQ + 128 : aQ + 64;   // fwd fl8,9  | bwd fl8,9

  float v[4];
  i32x4 bfr;

  // ---- init chain vector ----
  if (isFwd){
    const float2 ph0 = *(const float2*)phiRow;               // phi[0]
    #pragma unroll
    for (int reg = 0; reg < 4; ++reg){
      const int r = g*4 + reg;
      v[reg] = ph0.x * core_first[r] + ph0.y * core_first[16 + r];
    }
  } else {
    const float2 phL2 = *(const float2*)(phiRow + 510);      // phi[255]
    #pragma unroll
    for (int reg = 0; reg < 4; ++reg){
      const int r = g*4 + reg;
      v[reg] = phL2.x * core_last[2*r] + phL2.y * core_last[2*r + 1];
    }
  }
  make_bfrag(v, bfr);

  // ---- 4 rotating pair-fragment register sets + 2 phi windows ----
  i32x4 S0g0,S0g1,S0g2,S0g3, S1g0,S1g1,S1g2,S1g3;
  i32x4 S2g0,S2g1,S2g2,S2g3, S3g0,S3g1,S3g2,S3g3;
  f32x4 P0, P1;

  #define FRAG_LOAD(S, j) do { \
    const i32x4* s_ = wsLane + ((j) > maxPr ? maxPr : (j)) * 256; \
    S##g0 = s_[0]; S##g1 = s_[64]; S##g2 = s_[128]; S##g3 = s_[192]; } while(0)

  #define PHI_LOAD(P, cn) do { \
    const int cc_ = (cn) > 31 ? 31 : (cn); \
    P = *(const f32x4*)(phiSrc + (isFwd ? 8*cc_ : 496 - 8*cc_)); } while(0)

  #define SPULL(P, e, adr) __int_as_float(__builtin_amdgcn_ds_bpermute((adr), __float_as_int(P[e])))
  #define COEFFS(P, xA0_, xB0_, xA1_, xB1_) do { \
    xA0_ = make_float2(SPULL(P,2,adrA0), SPULL(P,3,adrA0)); \
    xB0_ = make_float2(SPULL(P,0,adrB0), SPULL(P,1,adrB0)); \
    xA1_ = make_float2(SPULL(P,2,adrA1), SPULL(P,3,adrA1)); \
    xB1_ = make_float2(SPULL(P,0,adrB1), SPULL(P,1,adrB1)); } while(0)

  // ---- prologue: establish queue [PHI(0)][F(0)][F(1)][PHI(1)][F(2)] = 14
  PHI_LOAD(P0, 0);
  FRAG_LOAD(S0, 0);
  FRAG_LOAD(S1, 1);
  PHI_LOAD(P1, 1);
  FRAG_LOAD(S2, 2);
  SB;

  #pragma unroll 1
  for (int t = 0; t < 16; ++t){
    // Loop-top invariant (oldest first):
    //   [PHI(2t)=P0,1][F(4t)=S0,4][F(4t+1)=S1,4][PHI(2t+1)=P1,1][F(4t+2)=S2,4] = 14
    float2 c0A, c0B, c1A, c1B, d0A, d0B, d1A, d1B;

    // step1: retire PHI(2t)+F(4t); compute pair 4t
    WAIT9;
    COEFFS(P0, c0A, c0B, c1A, c1B);            // chunk 2t coefficients
    pair_step(S0g0,S0g1,S0g2,S0g3, c0A, c0B, v, bfr);
    // step2: issue F(4t+3) -> outstanding 13
    FRAG_LOAD(S3, 4*t + 3); SB;
    // step3: retire F(4t+1); compute pair 4t+1
    WAIT9;
    pair_step(S1g0,S1g1,S1g2,S1g3, c1A, c1B, v, bfr);
    // step4: issue PHI(2t+2), F(4t+4) -> outstanding 14
    PHI_LOAD(P0, 2*t + 2); FRAG_LOAD(S0, 4*t + 4); SB;
    // step5: retire PHI(2t+1)+F(4t+2); compute pair 4t+2
    WAIT9;
    COEFFS(P1, d0A, d0B, d1A, d1B);            // chunk 2t+1 coefficients
    pair_step(S2g0,S2g1,S2g2,S2g3, d0A, d0B, v, bfr);
    // step6: issue F(4t+5) -> outstanding 13
    FRAG_LOAD(S1, 4*t + 5); SB;
    // step7: retire F(4t+3); compute pair 4t+3 (bwd skips pair 63)
    WAIT9;
    if (isFwd || (4*t + 3) < NPB)
      pair_step(S3g0,S3g1,S3g2,S3g3, d1A, d1B, v, bfr);
    // step8: issue PHI(2t+3), F(4t+6) -> outstanding 14 (= invariant @ t+1)
    PHI_LOAD(P1, 2*t + 3); FRAG_LOAD(S2, 4*t + 6); SB;
  }

  asm volatile("s_waitcnt vmcnt(0)" ::: "memory");
  __builtin_amdgcn_sched_barrier(0);

  // ---- epilogue: cross-wave reduction ----
  *(float4*)&red[(dirIdx*32 + s_in)*20 + 4*g] =
      make_float4(v[0], v[1], v[2], v[3]);
  __syncthreads();
  if (threadIdx.x < 32){
    const int s = threadIdx.x;
    float acc = bias[0];
    #pragma unroll
    for (int qq = 0; qq < 16; ++qq)
      acc += red[s*20 + qq] * red[(32 + s)*20 + qq];
    out[b0 + s] = acc;
  }

  #undef FRAG_LOAD
  #undef PHI_LOAD
  #undef SPULL
  #undef COEFFS
}

extern "C" void kernel_launch(void* const* d_in, const int* in_sizes, int n_in,
                              void* d_out, int out_size, void* d_ws, size_t ws_size,
                              hipStream_t stream)
{
  const float* phi  = (const float*)d_in[0];  // [32768,256,2]
  const float* cf   = (const float*)d_in[1];  // [2,16]
  const float* cm   = (const float*)d_in[2];  // [254,16,2,16]
  const float* cl   = (const float*)d_in[3];  // [16,2]
  const float* bias = (const float*)d_in[4];  // scalar
  i32x4* ws = (i32x4*)d_ws;                   // (64+63)*4*64*16B = 508 KB

  build_pair_frags<<<NPF + NPB, 256, 0, stream>>>(cm, ws);
  mps_chain<<<1024, 256, 0, stream>>>(phi, cf, cl, bias, ws, (float*)d_out);
}